// Round 10
// baseline (190.373 us; speedup 1.0000x reference)
//
#include <hip/hip_runtime.h>
#include <hip/hip_fp16.h>

// DiffusionConv: out = x@Tf0 + Px@(Tb0+Tb1) + P2x@(Tf1+Tb2) + P3x@Tf2
// R24: R23's FETCH=20MB confirmed the slice-major + XCD-pinning fetch fix
// (3rd confirmation); the remaining prop regression vs R18 is META
// DUPLICATION: 4 slice-blocks on 4 XCDs each fetch the node's 128B bucket
// line -> 25.6MB. Fix: CSR-pack the decoded meta.
//  - build: LDS scan of the 256 per-row counts -> loc[node] + tot[p]
//    (free, same kernel).
//  - scan2 (1 tiny block): exclusive scan of 196 partition totals -> btot.
//  - decode: writes bkt2 CSR-packed at btot[p]+loc[node]+j.
//  - prop: meta base = btot[node>>8]+loc[node]; a tile's meta is a ~1KB
//    contiguous stream (16 contiguous nodes) instead of 16 strided lines.
// Slice-major tables, XCD pinning, Phase A/B 8-deep-MLP prop, gemm:
// byte-identical to R23 (passed, absmax 0.03125).

#define N_NODES 50000
#define N_EDGES 800000
#define C 64
#define CAP 64          // bucket capacity; rows ~ Poisson(16), P(>64) ~ 2e-18
#define NPART 196       // partitions of 256 rows: p = r >> 8
#define CAPP 4608       // edges per partition region; mean 4096, +8 sigma
#define EPB 8192        // edges per block in scatter2
#define NEB 98          // ceil(800000/8192)
#define XH_BLOCKS 782   // ceil(800000 float4 chunks / 1024)
#define CW_BLOCKS 16    // 16384 weight elems / 1024
#define NPADL 50176
#define NSLICE 4        // channel slices of 16; slice = blockIdx&3
#define PB 3125         // node tiles of 16: 50000/16 exactly
#define GB 782          // ceil(50000/64) gemm row-tiles

typedef _Float16 half8 __attribute__((ext_vector_type(8)));
typedef float f32x4 __attribute__((ext_vector_type(4)));

// Fused: blocks [0,NEB): hist+reserve+scatter; [NEB,NEB+XH): x fp32->fp16
// into slice-major xh[4][NPADL][16]; [NEB+XH,..): weights -> whc[j][co][ci]
__global__ __launch_bounds__(1024) void scatter2_kernel(
        const int* __restrict__ row, const int* __restrict__ col,
        const float* __restrict__ w, int* __restrict__ percur,
        uint2* __restrict__ pedges,
        const float* __restrict__ x, __half* __restrict__ xh,
        const float* __restrict__ tf, const float* __restrict__ tb,
        _Float16* __restrict__ whc) {
    const int tid = threadIdx.x;
    if (blockIdx.x >= NEB + XH_BLOCKS) {
        int idx = (blockIdx.x - NEB - XH_BLOCKS) * 1024 + tid;  // < 16384
        int j = idx >> 12;
        int rem = idx & 4095;   // ci*64 + co
        int ci = rem >> 6;
        int co = rem & 63;
        float v;
        if (j == 0)      v = tf[rem];                         // Tf0
        else if (j == 1) v = tb[rem] + tb[4096 + rem];        // Tb0 + Tb1
        else if (j == 2) v = tf[4096 + rem] + tb[8192 + rem]; // Tf1 + Tb2
        else             v = tf[8192 + rem];                  // Tf2
        whc[(j << 12) + (co << 6) + ci] = (_Float16)v;        // transposed
        return;
    }
    if (blockIdx.x >= NEB) {
        int i = (blockIdx.x - NEB) * 1024 + tid;
        if (i < N_NODES * C / 4) {
            float4 v = ((const float4*)x)[i];
            union { float2 f2; __half2 h2[2]; } u;
            u.h2[0] = __floats2half2_rn(v.x, v.y);
            u.h2[1] = __floats2half2_rn(v.z, v.w);
            int node = i >> 4;
            int ci0 = (i & 15) << 2;            // 0,4,...,60
            int slice = ci0 >> 4;
            int off = ci0 & 15;                 // 0,4,8,12
            *(float2*)(void*)(xh + (((size_t)slice * NPADL + node) << 4) + off)
                = u.f2;
        }
        return;
    }
    __shared__ int h[NPART];
    __shared__ int cur[NPART];
    uint2 ent[8];
    int pp[8];
    if (tid < NPART) h[tid] = 0;
    __syncthreads();
    int base = blockIdx.x * EPB;
#pragma unroll
    for (int i = 0; i < 8; ++i) {
        int e = base + i * 1024 + tid;
        pp[i] = -1;
        if (e < N_EDGES) {
            int r = row[e];
            unsigned int c = (unsigned int)col[e];
            unsigned int wh = (unsigned int)__half_as_ushort(__float2half_rn(w[e]));
            ent[i] = make_uint2((c << 16) | wh, (unsigned int)(r & 255));
            pp[i] = r >> 8;
            atomicAdd(&h[pp[i]], 1);
        }
    }
    __syncthreads();
    if (tid < NPART) cur[tid] = atomicAdd(&percur[tid], h[tid]);
    __syncthreads();
#pragma unroll
    for (int i = 0; i < 8; ++i) {
        if (pp[i] >= 0) {
            int slot = atomicAdd(&cur[pp[i]], 1);
            pedges[(size_t)pp[i] * CAPP + slot] = ent[i];
        }
    }
}

// One block per partition: LDS-bin 256 rows x 64 slots, fuse dinv, sparse
// dump, PLUS: LDS scan of the 256 clamped counts -> loc[] (block-local
// exclusive offsets) and tot[p] (partition total) for CSR packing.
__global__ __launch_bounds__(1024) void build_kernel(
        const uint2* __restrict__ pedges, const int* __restrict__ percur,
        unsigned int* __restrict__ bkt, int* __restrict__ cnt,
        float* __restrict__ dinv, int* __restrict__ loc,
        int* __restrict__ tot) {
    __shared__ unsigned int lbuck[256 * CAP];   // 64 KB
    __shared__ int lcnt[256];
    __shared__ int sscan[256];
    const int tid = threadIdx.x;
    const int p = blockIdx.x;
    if (tid < 256) lcnt[tid] = 0;
    __syncthreads();
    int e = min(percur[p], CAPP);
    const uint2* src = pedges + (size_t)p * CAPP;
    for (int i = tid; i < e; i += 1024) {
        uint2 en = src[i];
        int rl = (int)en.y;
        int slot = atomicAdd(&lcnt[rl], 1);
        if (slot < CAP) lbuck[(rl << 6) + slot] = en.x;
    }
    __syncthreads();
    if (tid < 256) {
        int m = min(lcnt[tid], CAP);
        int g = (p << 8) + tid;
        float sum = 0.f;
        for (int j = 0; j < m; ++j)
            sum += __half2float(__ushort_as_half(
                (unsigned short)(lbuck[(tid << 6) + j] & 0xFFFFu)));
        if (g < N_NODES) {
            cnt[g] = m;
            dinv[g] = (sum > 0.f) ? rsqrtf(sum) : 0.f;
        }
        sscan[tid] = m;        // pad rows naturally 0 (lcnt init, no edges)
    }
    __syncthreads();
    // Hillis-Steele inclusive scan over 256 (all threads hit barriers)
#pragma unroll
    for (int d = 1; d < 256; d <<= 1) {
        int t = 0;
        if (tid < 256 && tid >= d) t = sscan[tid - d];
        __syncthreads();
        if (tid < 256) sscan[tid] += t;
        __syncthreads();
    }
    if (tid < 256) {
        int m = min(lcnt[tid], CAP);
        loc[(p << 8) + tid] = sscan[tid] - m;   // exclusive
        if (tid == 255) tot[p] = sscan[255];
    }
    __syncthreads();
    // sparse dump: 4 threads per row, chunk = tid&3; only ceil(m/4) uint4s
    {
        int r = tid >> 2;
        int ch = tid & 3;
        int m = min(lcnt[r], CAP);
        const uint4* s4 = (const uint4*)&lbuck[r << 6];
        uint4* dst = (uint4*)(bkt + (((size_t)(p << 8) + r) << 6));
        for (int j = ch; (j << 2) < m; j += 4) dst[j] = s4[j];
    }
}

// Exclusive scan of the 196 partition totals -> btot (one tiny block).
__global__ __launch_bounds__(256) void scan2_kernel(
        const int* __restrict__ tot, int* __restrict__ btot) {
    __shared__ int s[256];
    const int tid = threadIdx.x;
    int v = (tid < NPART) ? tot[tid] : 0;
    s[tid] = v;
    __syncthreads();
#pragma unroll
    for (int d = 1; d < 256; d <<= 1) {
        int t = (tid >= d) ? s[tid - d] : 0;
        __syncthreads();
        s[tid] += t;
        __syncthreads();
    }
    if (tid < NPART) btot[tid] = s[tid] - v;
}

// Fold dinv[col] into the stored weight once, CSR-packed:
// bkt2[btot[p]+loc[node]+j] = (col<<16)|half(w*dinv[col])
__global__ __launch_bounds__(1024) void decode_kernel(
        const unsigned int* __restrict__ bkt, const int* __restrict__ cnt,
        const float* __restrict__ dinv, const int* __restrict__ loc,
        const int* __restrict__ btot, unsigned int* __restrict__ bkt2) {
    int e = blockIdx.x * 1024 + threadIdx.x;       // < NPADL*64
    int node = e >> 6;
    int j = e & 63;
    if (node < N_NODES && j < min(cnt[node], CAP)) {
        unsigned int b = bkt[e];
        int c = (int)(b >> 16);
        float nn = __half2float(__ushort_as_half((unsigned short)(b & 0xFFFFu)))
                   * dinv[c];
        bkt2[btot[node >> 8] + loc[node] + j] = ((unsigned int)c << 16) |
                  (unsigned int)__half_as_ushort(__float2half_rn(nn));
    }
}

// Slice-parallel prop, full-MLP schedule, CSR meta: block b -> slice b&3
// (16 ch), tile b>>2 (16 nodes). Wave = 4 nodes (quarter q); lane ql:
// u=ql>>2 edge subslot, cq=ql&3 channel quad. Meta prefetched to regs from
// the CSR stream (tile's 16 nodes contiguous -> ~1KB contiguous read).
// Phase A: edges 0..31, 8 INDEPENDENT 8B gathers in flight. Phase B
// (wave-uniform mx>32, P~1e-4): edges 32..63. Epilogue: 2-step shfl_xor
// over u; u==0 lanes write 8B.
__global__ __launch_bounds__(256) void prop_kernel(
        const __half* __restrict__ xin, __half* __restrict__ xout,
        const int* __restrict__ cnt, const unsigned int* __restrict__ bkt2,
        const float* __restrict__ dinv, const int* __restrict__ loc,
        const int* __restrict__ btot) {
    const int tid = threadIdx.x;
    const int wib = tid >> 6;
    const int lane = tid & 63;
    const int q = lane >> 4;
    const int ql = lane & 15;
    const int u = ql >> 2;
    const int cq = ql & 3;
    const int slice = blockIdx.x & 3;
    const int tile = blockIdx.x >> 2;
    const int node = (tile << 4) + (wib << 2) + q;   // < 50000 always
    const int m = min(cnt[node], CAP);
    const int csr = btot[node >> 8] + loc[node];
    // prefetch all (<=4) strided CSR entries for this lane (padded)
    int cj[4];
    float nj[4];
#pragma unroll
    for (int s = 0; s < 4; ++s) {
        int idx = (s << 4) + ql;
        cj[s] = 0;
        nj[s] = 0.f;
        if (idx < m) {
            unsigned int b = bkt2[csr + idx];
            cj[s] = (int)(b >> 16) << 4;             // row offset (16 halves/row)
            nj[s] = __half2float(__ushort_as_half((unsigned short)(b & 0xFFFFu)));
        }
    }
    int mx = m;
    mx = max(mx, __shfl_xor(mx, 16));
    mx = max(mx, __shfl_xor(mx, 32));                // max over wave's 4 nodes
    const __half* xsl = xin + ((size_t)slice * NPADL << 4);
    float a0 = 0.f, a1 = 0.f, a2 = 0.f, a3 = 0.f;
    // ---- Phase A: edges 0..31, 8 loads in flight ----
    {
        int cs[8];
        float ns[8];
        float2 vs[8];
#pragma unroll
        for (int g = 0; g < 2; ++g)
#pragma unroll
            for (int t = 0; t < 4; ++t) {
                int i = (g << 2) + t;
                int sl = (q << 4) + (t << 2) + u;    // edge g*16 + t*4+u
                cs[i] = __shfl(cj[g], sl);
                ns[i] = __shfl(nj[g], sl);
            }
#pragma unroll
        for (int i = 0; i < 8; ++i)
            vs[i] = *(const float2*)(xsl + cs[i] + (cq << 2));
#pragma unroll
        for (int i = 0; i < 8; ++i) {
            const __half2* hp = (const __half2*)&vs[i];
            float2 A = __half22float2(hp[0]);
            float2 B = __half22float2(hp[1]);
            a0 += ns[i] * A.x;
            a1 += ns[i] * A.y;
            a2 += ns[i] * B.x;
            a3 += ns[i] * B.y;
        }
    }
    // ---- Phase B: edges 32..63, rare ----
    if (mx > 32) {
        int cs[8];
        float ns[8];
        float2 vs[8];
#pragma unroll
        for (int g = 0; g < 2; ++g)
#pragma unroll
            for (int t = 0; t < 4; ++t) {
                int i = (g << 2) + t;
                int sl = (q << 4) + (t << 2) + u;
                cs[i] = __shfl(cj[2 + g], sl);
                ns[i] = __shfl(nj[2 + g], sl);
            }
#pragma unroll
        for (int i = 0; i < 8; ++i)
            vs[i] = *(const float2*)(xsl + cs[i] + (cq << 2));
#pragma unroll
        for (int i = 0; i < 8; ++i) {
            const __half2* hp = (const __half2*)&vs[i];
            float2 A = __half22float2(hp[0]);
            float2 B = __half22float2(hp[1]);
            a0 += ns[i] * A.x;
            a1 += ns[i] * A.y;
            a2 += ns[i] * B.x;
            a3 += ns[i] * B.y;
        }
    }
    // reduce over u (lane bits 2,3)
    a0 += __shfl_xor(a0, 4); a0 += __shfl_xor(a0, 8);
    a1 += __shfl_xor(a1, 4); a1 += __shfl_xor(a1, 8);
    a2 += __shfl_xor(a2, 4); a2 += __shfl_xor(a2, 8);
    a3 += __shfl_xor(a3, 4); a3 += __shfl_xor(a3, 8);
    if (u == 0) {
        float dr = dinv[node];
        union { float2 f2; __half2 h2[2]; } o;
        o.h2[0] = __floats2half2_rn(dr * a0, dr * a1);
        o.h2[1] = __floats2half2_rn(dr * a2, dr * a3);
        *(float2*)(void*)(xout + (((size_t)slice * NPADL + node) << 4)
                          + (cq << 2)) = o.f2;
    }
}

// MFMA GEMM: out[r][co] = sum_j Xj[r][:] @ Wc[j][:][co], slice-major A.
// A-frag: A[m=lane&15][k=quad*8+i]: k0=kk+8*quad -> slice k0>>4, off k0&15.
// B-frag: B[k][n=lane&15] from whc[j][n][k..]; C/D: col=lane&15, row=quad*4+reg.
__global__ __launch_bounds__(256) void gemm_mfma_kernel(
        const __half* __restrict__ x0, const __half* __restrict__ x1,
        const __half* __restrict__ x2, const __half* __restrict__ x3,
        const _Float16* __restrict__ whc, float* __restrict__ out) {
    const int tid = threadIdx.x;
    const int wv = tid >> 6;
    const int lane = tid & 63;
    const int quad = lane >> 4;
    const int l16 = lane & 15;
    const int mbase = (blockIdx.x << 6) + (wv << 4);
    const __half* srcs[4] = {x0, x1, x2, x3};
    f32x4 acc0 = {}, acc1 = {}, acc2 = {}, acc3 = {};
    const int arow = mbase + l16;
    const bool aok = arow < N_NODES;
    const half8 zero8 = {};
#pragma unroll
    for (int j = 0; j < 4; ++j) {
        const __half* src = srcs[j];
#pragma unroll
        for (int kk = 0; kk < 64; kk += 32) {
            const int k0 = kk + (quad << 3);
            const int slice = k0 >> 4;
            const int koff = k0 & 15;
            half8 af = aok ? *(const half8*)(const void*)(
                src + (((size_t)slice * NPADL + arow) << 4) + koff) : zero8;
            const _Float16* wb = whc + (j << 12) + kk + (quad << 3);
            half8 b0 = *(const half8*)(const void*)(wb + ((0 * 16 + l16) << 6));
            half8 b1 = *(const half8*)(const void*)(wb + ((1 * 16 + l16) << 6));
            half8 b2 = *(const half8*)(const void*)(wb + ((2 * 16 + l16) << 6));
            half8 b3 = *(const half8*)(const void*)(wb + ((3 * 16 + l16) << 6));
            acc0 = __builtin_amdgcn_mfma_f32_16x16x32_f16(af, b0, acc0, 0, 0, 0);
            acc1 = __builtin_amdgcn_mfma_f32_16x16x32_f16(af, b1, acc1, 0, 0, 0);
            acc2 = __builtin_amdgcn_mfma_f32_16x16x32_f16(af, b2, acc2, 0, 0, 0);
            acc3 = __builtin_amdgcn_mfma_f32_16x16x32_f16(af, b3, acc3, 0, 0, 0);
        }
    }
#pragma unroll
    for (int i = 0; i < 4; ++i) {
        int r = mbase + (quad << 2) + i;
        if (r < N_NODES) {
            float* dst = out + ((size_t)r << 6) + l16;
            dst[0]  = acc0[i];
            dst[16] = acc1[i];
            dst[32] = acc2[i];
            dst[48] = acc3[i];
        }
    }
}

extern "C" void kernel_launch(void* const* d_in, const int* in_sizes, int n_in,
                              void* d_out, int out_size, void* d_ws, size_t ws_size,
                              hipStream_t stream) {
    const float* x  = (const float*)d_in[0];
    const int*   ei = (const int*)d_in[1];   // row = ei[0..E), col = ei[E..2E)
    const float* ew = (const float*)d_in[2];
    const float* tf = (const float*)d_in[3];
    const float* tb = (const float*)d_in[4];
    float* out = (float*)d_out;

    const int* row = ei;
    const int* col = ei + N_EDGES;

    // workspace layout (4B words), total ~60 MB
    const size_t TBL = (size_t)NSLICE * NPADL * 16 / 2;   // words per table
    float* ws = (float*)d_ws;
    size_t off = 0;
    int*    percur = (int*)(ws + off); off += 256;
    int*    tot    = (int*)(ws + off); off += 256;
    int*    btot   = (int*)(ws + off); off += 256;
    uint2*  pedges = (uint2*)(ws + off); off += (size_t)NPART * CAPP * 2;
    unsigned int* bkt  = (unsigned int*)(ws + off); off += (size_t)NPADL * CAP;
    unsigned int* bkt2 = (unsigned int*)(ws + off); off += (size_t)NPADL * CAP;
    int*    cnt  = (int*)(ws + off); off += NPADL;
    int*    loc  = (int*)(ws + off); off += NPADL;
    float*  dinv = ws + off; off += NPADL;
    __half* xh   = (__half*)(ws + off); off += TBL;
    __half* tA   = (__half*)(ws + off); off += TBL;
    __half* tB   = (__half*)(ws + off); off += TBL;
    __half* tC   = (__half*)(ws + off); off += TBL;
    _Float16* whc = (_Float16*)(ws + off); off += 4 * 64 * 64 / 2;

    hipMemsetAsync(percur, 0, 256 * sizeof(int), stream);

    scatter2_kernel<<<NEB + XH_BLOCKS + CW_BLOCKS, 1024, 0, stream>>>(
        row, col, ew, percur, pedges, x, xh, tf, tb, whc);
    build_kernel<<<NPART, 1024, 0, stream>>>(pedges, percur, bkt, cnt, dinv,
                                             loc, tot);
    scan2_kernel<<<1, 256, 0, stream>>>(tot, btot);
    decode_kernel<<<NPADL * CAP / 1024, 1024, 0, stream>>>(
        bkt, cnt, dinv, loc, btot, bkt2);

    prop_kernel<<<NSLICE * PB, 256, 0, stream>>>(
        xh, tA, cnt, bkt2, dinv, loc, btot);   // tx1
    prop_kernel<<<NSLICE * PB, 256, 0, stream>>>(
        tA, tB, cnt, bkt2, dinv, loc, btot);   // tx2
    prop_kernel<<<NSLICE * PB, 256, 0, stream>>>(
        tB, tC, cnt, bkt2, dinv, loc, btot);   // tx3

    gemm_mfma_kernel<<<GB, 256, 0, stream>>>(xh, tA, tB, tC, whc, out);
}

// Round 11
// 157.177 us; speedup vs baseline: 1.2112x; 1.2112x over previous
//
#include <hip/hip_runtime.h>
#include <hip/hip_fp16.h>

// DiffusionConv: out = x@Tf0 + Px@(Tb0+Tb1) + P2x@(Tf1+Tb2) + P3x@Tf2
// R25: revert to R18 (best verified, 158.9us). Session evidence:
//  - prop floor ~29us/prop is structural: random 128B-row gathers from a
//    6.4MB table through 8 non-coherent XCD L2s with L3 poisoned per iter
//    => ~42MB compulsory HBM lines at ~1.4TB/s (outstanding-miss limit).
//    Falsified alternatives: wider loads (R20, neutral), deeper MLP (R20/
//    R23, neutral), slice-major fetch reduction 42->20MB (R22/R23/R24,
//    net LOSS from 4x meta/epilogue overhead), direct-atomic scatter
//    (R17, +27us), persistent fused props (R21, +500us).
//  - R18 structure: scatter2 (EPB 8192) + build (sparse dump) + prop1
//    (FIXW folds w*dinv[col] into bkt) + prop2 + prop3-with-fused-MFMA-gemm.
// Budget: 45us harness fill + ~87us props (HW floor) + ~22us scatter chain
// + ~5us rest = ~159us.

#define N_NODES 50000
#define N_EDGES 800000
#define C 64
#define CAP 64          // bucket capacity; rows ~ Poisson(16), P(>64) ~ 2e-18
#define NPART 196       // partitions of 256 rows: p = r >> 8
#define CAPP 4608       // edges per partition region; mean 4096, +8 sigma
#define EPB 8192        // edges per block in scatter2
#define NEB 98          // ceil(800000/8192)
#define XH_BLOCKS 782   // ceil(800000 float4 chunks / 1024)
#define CW_BLOCKS 16    // 16384 weight elems / 1024

typedef _Float16 half8 __attribute__((ext_vector_type(8)));
typedef float f32x4 __attribute__((ext_vector_type(4)));

// Fused: blocks [0,NEB): hist+reserve+scatter; [NEB,NEB+XH): x fp32->fp16;
// [NEB+XH,..): combined weights -> fp16 transposed whc[j][co][ci]
__global__ __launch_bounds__(1024) void scatter2_kernel(
        const int* __restrict__ row, const int* __restrict__ col,
        const float* __restrict__ w, int* __restrict__ percur,
        uint2* __restrict__ pedges,
        const float* __restrict__ x, __half* __restrict__ xh,
        const float* __restrict__ tf, const float* __restrict__ tb,
        _Float16* __restrict__ whc) {
    const int tid = threadIdx.x;
    if (blockIdx.x >= NEB + XH_BLOCKS) {
        int idx = (blockIdx.x - NEB - XH_BLOCKS) * 1024 + tid;  // < 16384
        int j = idx >> 12;
        int rem = idx & 4095;   // ci*64 + co
        int ci = rem >> 6;
        int co = rem & 63;
        float v;
        if (j == 0)      v = tf[rem];                         // Tf0
        else if (j == 1) v = tb[rem] + tb[4096 + rem];        // Tb0 + Tb1
        else if (j == 2) v = tf[4096 + rem] + tb[8192 + rem]; // Tf1 + Tb2
        else             v = tf[8192 + rem];                  // Tf2
        whc[(j << 12) + (co << 6) + ci] = (_Float16)v;        // transposed
        return;
    }
    if (blockIdx.x >= NEB) {
        int i = (blockIdx.x - NEB) * 1024 + tid;
        if (i < N_NODES * C / 4) {
            float4 v = ((const float4*)x)[i];
            union { float2 f2; __half2 h2[2]; } u;
            u.h2[0] = __floats2half2_rn(v.x, v.y);
            u.h2[1] = __floats2half2_rn(v.z, v.w);
            ((float2*)xh)[i] = u.f2;
        }
        return;
    }
    __shared__ int h[NPART];
    __shared__ int cur[NPART];
    uint2 ent[8];
    int pp[8];
    if (tid < NPART) h[tid] = 0;
    __syncthreads();
    int base = blockIdx.x * EPB;
#pragma unroll
    for (int i = 0; i < 8; ++i) {
        int e = base + i * 1024 + tid;
        pp[i] = -1;
        if (e < N_EDGES) {
            int r = row[e];
            unsigned int c = (unsigned int)col[e];
            unsigned int wh = (unsigned int)__half_as_ushort(__float2half_rn(w[e]));
            ent[i] = make_uint2((c << 16) | wh, (unsigned int)(r & 255));
            pp[i] = r >> 8;
            atomicAdd(&h[pp[i]], 1);
        }
    }
    __syncthreads();
    if (tid < NPART) cur[tid] = atomicAdd(&percur[tid], h[tid]);
    __syncthreads();
#pragma unroll
    for (int i = 0; i < 8; ++i) {
        if (pp[i] >= 0) {
            int slot = atomicAdd(&cur[pp[i]], 1);
            pedges[(size_t)pp[i] * CAPP + slot] = ent[i];
        }
    }
}

// One block per partition: LDS-bin 256 rows x 64 slots, fuse dinv,
// dump only the used slot prefix per row (uint4 chunks).
__global__ __launch_bounds__(1024) void build_kernel(
        const uint2* __restrict__ pedges, const int* __restrict__ percur,
        unsigned int* __restrict__ bkt, int* __restrict__ cnt,
        float* __restrict__ dinv) {
    __shared__ unsigned int lbuck[256 * CAP];   // 64 KB
    __shared__ int lcnt[256];
    const int tid = threadIdx.x;
    const int p = blockIdx.x;
    if (tid < 256) lcnt[tid] = 0;
    __syncthreads();
    int e = min(percur[p], CAPP);
    const uint2* src = pedges + (size_t)p * CAPP;
    for (int i = tid; i < e; i += 1024) {
        uint2 en = src[i];
        int rl = (int)en.y;
        int slot = atomicAdd(&lcnt[rl], 1);
        if (slot < CAP) lbuck[(rl << 6) + slot] = en.x;
    }
    __syncthreads();
    if (tid < 256) {
        int m = min(lcnt[tid], CAP);
        int g = (p << 8) + tid;
        float sum = 0.f;
        for (int j = 0; j < m; ++j)
            sum += __half2float(__ushort_as_half(
                (unsigned short)(lbuck[(tid << 6) + j] & 0xFFFFu)));
        if (g < N_NODES) {
            cnt[g] = m;
            dinv[g] = (sum > 0.f) ? rsqrtf(sum) : 0.f;
        }
    }
    __syncthreads();
    // sparse dump: 4 threads per row, chunk = tid&3; only ceil(m/4) uint4s
    {
        int r = tid >> 2;
        int ch = tid & 3;
        int m = min(lcnt[r], CAP);
        const uint4* s4 = (const uint4*)&lbuck[r << 6];
        uint4* dst = (uint4*)(bkt + (((size_t)(p << 8) + r) << 6));
        for (int j = ch; (j << 2) < m; j += 4) dst[j] = s4[j];
    }
}

// 4 nodes per wave: quarter q owns node wave*4+q; lane ql (0-15) holds
// channels 4ql..4ql+3. Bucket meta prefetched upfront (<=4 entries/lane).
// FIXW (prop1): n = w * dinv[col], written back into bkt so later props
//   read the normalized weight directly (no dinv gather).
// FUSE_GEMM (prop3): block's 16 rows = one MFMA tile; tC rows staged in LDS
//   (stride 72 halves => conflict-light ds_read_b128), then each wave
//   computes a 16-col block of out = xh@W0 + tA@W1 + tB@W2 + tC@W3.
template <bool FIXW, bool FUSE_GEMM>
__global__ __launch_bounds__(256) void prop_kernel(
        const __half* __restrict__ xin, __half* __restrict__ xout,
        const int* __restrict__ cnt, unsigned int* __restrict__ bkt,
        const float* __restrict__ dinv,
        const __half* __restrict__ x0, const __half* __restrict__ x1,
        const _Float16* __restrict__ whc, float* __restrict__ out) {
    const int tid = threadIdx.x;
    const int wib = tid >> 6;
    const int lane = tid & 63;
    const int q = lane >> 4;
    const int ql = lane & 15;
    const int node = (blockIdx.x << 4) + (wib << 2) + q;  // < 50000 always
    int m = min(cnt[node], CAP);
    int base = node << 6;
    // prefetch all (<=4) strided bucket entries for this lane
    int cj[4];
    float nj[4];
#pragma unroll
    for (int s = 0; s < 4; ++s) {
        int idx = (s << 4) + ql;
        cj[s] = 0;
        nj[s] = 0.f;
        if (idx < m) {
            unsigned int b = bkt[base + idx];
            int c = (int)(b >> 16);
            cj[s] = c << 6;                                // half-elem row offset
            float wv = __half2float(__ushort_as_half((unsigned short)(b & 0xFFFFu)));
            if constexpr (FIXW) {
                float nn = wv * dinv[c];
                nj[s] = nn;
                bkt[base + idx] = ((unsigned int)c << 16) |
                    (unsigned int)__half_as_ushort(__float2half_rn(nn));
            } else {
                nj[s] = wv;
            }
        }
    }
    float ax = 0.f, ay = 0.f, az = 0.f, aw = 0.f;
#pragma unroll
    for (int s = 0; s < 4; ++s) {
        int cb = s << 4;
        if (cb >= m) break;
        int rem = m - cb;
        if (rem > 16) rem = 16;
        int mm = (rem + 7) & ~7;    // padded lanes carry cj=0,nj=0
        for (int jo = 0; jo < mm; jo += 8) {
            int cs[8];
            float ns[8];
            float2 vs[8];
#pragma unroll
            for (int t = 0; t < 8; ++t) {
                cs[t] = __shfl(cj[s], (q << 4) + jo + t);
                ns[t] = __shfl(nj[s], (q << 4) + jo + t);
            }
#pragma unroll
            for (int t = 0; t < 8; ++t)
                vs[t] = *(const float2*)(xin + cs[t] + (ql << 2));
#pragma unroll
            for (int t = 0; t < 8; ++t) {
                const __half2* hp = (const __half2*)&vs[t];
                float2 a = __half22float2(hp[0]);
                float2 b = __half22float2(hp[1]);
                ax += ns[t] * a.x;
                ay += ns[t] * a.y;
                az += ns[t] * b.x;
                aw += ns[t] * b.y;
            }
        }
    }
    float dr = dinv[node];
    union { float2 f2; __half2 h2[2]; } u;
    u.h2[0] = __floats2half2_rn(dr * ax, dr * ay);
    u.h2[1] = __floats2half2_rn(dr * az, dr * aw);
    if constexpr (!FUSE_GEMM) {
        *(float2*)(xout + ((size_t)node << 6) + (ql << 2)) = u.f2;
    } else {
        __shared__ _Float16 tcl[16 * 72];   // 16 rows, stride 72 halves (2.3KB)
        // row r_loc = wib*4+q, channels 4ql..4ql+3
        *(float2*)(void*)&tcl[((wib << 2) + q) * 72 + (ql << 2)] = u.f2;
        __syncthreads();
        // ---- fused MFMA GEMM for this block's 16-row tile ----
        // A-frag: A[m=lane&15][k=quad*8+i]; B-frag: B[k][n=lane&15] from
        // transposed whc[j][n][k]; C/D: col=lane&15, row=quad*4+reg.
        // wave wib handles output cols [16*wib, 16*wib+16).
        const int mbase = blockIdx.x << 4;
        const __half* gsrc[3] = {x0, x1, xin};   // xh, tA, tB
        const size_t abase = ((size_t)(mbase + ql) << 6) + (q << 3);
        f32x4 acc = {};
#pragma unroll
        for (int j = 0; j < 4; ++j) {
#pragma unroll
            for (int kk = 0; kk < 64; kk += 32) {
                half8 af;
                if (j < 3)
                    af = *(const half8*)(const void*)(gsrc[j] + abase + kk);
                else
                    af = *(const half8*)(const void*)&tcl[ql * 72 + (q << 3) + kk];
                const _Float16* wb = whc + (j << 12) + (((wib << 4) + ql) << 6)
                                         + (q << 3) + kk;
                half8 bf = *(const half8*)(const void*)wb;
                acc = __builtin_amdgcn_mfma_f32_16x16x32_f16(af, bf, acc, 0, 0, 0);
            }
        }
#pragma unroll
        for (int i = 0; i < 4; ++i) {
            int r = mbase + (q << 2) + i;
            out[((size_t)r << 6) + (wib << 4) + ql] = acc[i];
        }
    }
}

extern "C" void kernel_launch(void* const* d_in, const int* in_sizes, int n_in,
                              void* d_out, int out_size, void* d_ws, size_t ws_size,
                              hipStream_t stream) {
    const float* x  = (const float*)d_in[0];
    const int*   ei = (const int*)d_in[1];   // row = ei[0..E), col = ei[E..2E)
    const float* ew = (const float*)d_in[2];
    const float* tf = (const float*)d_in[3];
    const float* tb = (const float*)d_in[4];
    float* out = (float*)d_out;

    const int* row = ei;
    const int* col = ei + N_EDGES;

    // workspace layout (4B words), total ~46 MB
    const int NROWS_PAD = NPART * 256;   // 50176
    float* ws = (float*)d_ws;
    size_t off = 0;
    int*    percur = (int*)(ws + off); off += 256;
    uint2*  pedges = (uint2*)(ws + off); off += (size_t)NPART * CAPP * 2;
    unsigned int* bkt = (unsigned int*)(ws + off); off += (size_t)NROWS_PAD * CAP;
    int*    cnt  = (int*)(ws + off); off += NROWS_PAD;
    float*  dinv = ws + off; off += NROWS_PAD;
    __half* xh   = (__half*)(ws + off); off += (size_t)N_NODES * C / 2;
    __half* tA   = (__half*)(ws + off); off += (size_t)N_NODES * C / 2;
    __half* tB   = (__half*)(ws + off); off += (size_t)N_NODES * C / 2;
    __half* tC   = (__half*)(ws + off); off += (size_t)N_NODES * C / 2;
    _Float16* whc = (_Float16*)(ws + off); off += 4 * 64 * 64 / 2;

    hipMemsetAsync(percur, 0, 256 * sizeof(int), stream);

    scatter2_kernel<<<NEB + XH_BLOCKS + CW_BLOCKS, 1024, 0, stream>>>(
        row, col, ew, percur, pedges, x, xh, tf, tb, whc);
    build_kernel<<<NPART, 1024, 0, stream>>>(pedges, percur, bkt, cnt, dinv);

    const int PB = N_NODES / 16;   // 3125 blocks, 16 nodes each (exact)
    prop_kernel<true,  false><<<PB, 256, 0, stream>>>(
        xh, tA, cnt, bkt, dinv, nullptr, nullptr, nullptr, nullptr);   // tx1
    prop_kernel<false, false><<<PB, 256, 0, stream>>>(
        tA, tB, cnt, bkt, dinv, nullptr, nullptr, nullptr, nullptr);   // tx2
    prop_kernel<false, true><<<PB, 256, 0, stream>>>(
        tB, tC, cnt, bkt, dinv, xh, tA, whc, out);                     // tx3+gemm
}